// Round 2
// baseline (70.311 us; speedup 1.0000x reference)
//
#include <hip/hip_runtime.h>

namespace {
constexpr int kB = 32, kT = 30, kD = 512, kL = 196;
constexpr float kK = 2.8853900817779268f;  // 2*log2(e)
constexpr int kLQ = 28;                    // l per score block (7 tiles)
constexpr int kDSl = 64;                   // d per score block (8 slices)
constexpr int kStr = 66;                   // LDS row stride (floats): 2-way bank alias = free, 8B aligned
constexpr int kTL = kT * kL;               // 5880

// g_part[ds][b][l][t] = sum over d-slice of vw_d / (E*F + 1)
__global__ __launch_bounds__(896) void k_score(
    const float* __restrict__ x, const float* __restrict__ w,
    const float* __restrict__ img, const float* __restrict__ vw,
    float* __restrict__ g_part) {
  __shared__ float Elds[32 * kStr];
  __shared__ float Flds[kLQ * kStr];
  __shared__ __align__(16) float vwl[kDSl];
  const int lq = blockIdx.x, ds = blockIdx.y, b = blockIdx.z;
  const int l0 = lq * kLQ, d0 = ds * kDSl;
  const int tid = threadIdx.x;
  // stage E = exp2(kK*(x+w)) for all 30 t (rows 30,31 = 1.0 for dead lanes)
  for (int i = tid; i < 32 * kDSl; i += 896) {
    const int t = i >> 6, d = i & 63;
    float v = 1.0f;
    if (t < kT) {
      const size_t gi = ((size_t)(b * kT + t)) * kD + d0 + d;
      v = __builtin_amdgcn_exp2f(kK * (x[gi] + w[gi]));
    }
    Elds[t * kStr + d] = v;
  }
  // stage F = exp2(kK*img) for the 28 l of this tile
  for (int i = tid; i < kLQ * kDSl; i += 896) {
    const int r = i >> 6, d = i & 63;
    const size_t gi = ((size_t)(b * kL + l0 + r)) * kD + d0 + d;
    Flds[r * kStr + d] = __builtin_amdgcn_exp2f(kK * img[gi]);
  }
  if (tid < kDSl) vwl[tid] = vw[d0 + tid];
  __syncthreads();
  const int lane = tid & 63, wv = tid >> 6;  // wv in [0,14)
  const int t = lane & 31, ls = lane >> 5;   // lane = (t, l-sub); t=30,31 dead (6%)
  const float* Er = &Elds[t * kStr];
  const float* Fr = &Flds[(2 * wv + ls) * kStr];
  float a0 = 0.f, a1 = 0.f, a2 = 0.f, a3 = 0.f;
#pragma unroll
  for (int dc = 0; dc < kDSl; dc += 8) {
    const float2 e01 = *(const float2*)(Er + dc);
    const float2 e23 = *(const float2*)(Er + dc + 2);
    const float2 e45 = *(const float2*)(Er + dc + 4);
    const float2 e67 = *(const float2*)(Er + dc + 6);
    const float2 f01 = *(const float2*)(Fr + dc);
    const float2 f23 = *(const float2*)(Fr + dc + 2);
    const float2 f45 = *(const float2*)(Fr + dc + 4);
    const float2 f67 = *(const float2*)(Fr + dc + 6);
    const float4 v03 = *(const float4*)(vwl + dc);
    const float4 v47 = *(const float4*)(vwl + dc + 4);
    const float r0 = __builtin_amdgcn_rcpf(fmaf(e01.x, f01.x, 1.0f));
    const float r1 = __builtin_amdgcn_rcpf(fmaf(e01.y, f01.y, 1.0f));
    const float r2 = __builtin_amdgcn_rcpf(fmaf(e23.x, f23.x, 1.0f));
    const float r3 = __builtin_amdgcn_rcpf(fmaf(e23.y, f23.y, 1.0f));
    const float r4 = __builtin_amdgcn_rcpf(fmaf(e45.x, f45.x, 1.0f));
    const float r5 = __builtin_amdgcn_rcpf(fmaf(e45.y, f45.y, 1.0f));
    const float r6 = __builtin_amdgcn_rcpf(fmaf(e67.x, f67.x, 1.0f));
    const float r7 = __builtin_amdgcn_rcpf(fmaf(e67.y, f67.y, 1.0f));
    a0 = fmaf(v03.x, r0, a0);
    a1 = fmaf(v03.y, r1, a1);
    a2 = fmaf(v03.z, r2, a2);
    a3 = fmaf(v03.w, r3, a3);
    a0 = fmaf(v47.x, r4, a0);
    a1 = fmaf(v47.y, r5, a1);
    a2 = fmaf(v47.z, r6, a2);
    a3 = fmaf(v47.w, r7, a3);
  }
  if (t < kT) {
    const int l = l0 + 2 * wv + ls;
    g_part[(((size_t)ds * kB + b) * kL + l) * kT + t] = (a0 + a1) + (a2 + a3);
  }
}

// sum 8 partials, softmax over l, write alphaT[b][l][t]
__global__ __launch_bounds__(256) void k_alpha(
    const float* __restrict__ g_part, float* __restrict__ alphaT) {
  __shared__ __align__(16) float u[kTL];
  const int b = blockIdx.x, tid = threadIdx.x;
  for (int s4 = tid; s4 < kTL / 4; s4 += 256) {
    float4 a = {0.f, 0.f, 0.f, 0.f};
#pragma unroll
    for (int ds = 0; ds < 8; ++ds) {
      const float4 g =
          *(const float4*)&g_part[((size_t)ds * kB + b) * kTL + 4 * s4];
      a.x += g.x; a.y += g.y; a.z += g.z; a.w += g.w;
    }
    *(float4*)&u[4 * s4] = a;
  }
  __syncthreads();
  const int lane = tid & 63, wv = tid >> 6;
  for (int t = wv; t < kT; t += 4) {
    // q = kK*g ; alpha ~ exp2(min(q) - q)
    const float q0 = u[lane * kT + t] * kK;
    const float q1 = u[(lane + 64) * kT + t] * kK;
    const float q2 = u[(lane + 128) * kT + t] * kK;
    const float q3 = (lane < kL - 192) ? u[(lane + 192) * kT + t] * kK
                                       : __builtin_inff();
    float m = fminf(fminf(q0, q1), fminf(q2, q3));
#pragma unroll
    for (int mm = 1; mm < 64; mm <<= 1) m = fminf(m, __shfl_xor(m, mm, 64));
    const float e0 = __builtin_amdgcn_exp2f(m - q0);
    const float e1 = __builtin_amdgcn_exp2f(m - q1);
    const float e2 = __builtin_amdgcn_exp2f(m - q2);
    const float e3 =
        (lane < kL - 192) ? __builtin_amdgcn_exp2f(m - q3) : 0.f;
    float s = e0 + e1 + e2 + e3;
#pragma unroll
    for (int mm = 1; mm < 64; mm <<= 1) s += __shfl_xor(s, mm, 64);
    const float rs = __builtin_amdgcn_rcpf(s);
    float* ab = alphaT + (size_t)b * kTL + t;
    ab[lane * kT] = e0 * rs;
    ab[(lane + 64) * kT] = e1 * rs;
    ab[(lane + 128) * kT] = e2 * rs;
    if (lane < kL - 192) ab[(lane + 192) * kT] = e3 * rs;
  }
}

// context[b][t][d] = sum_l img[b][l][d] * alphaT[b][l][t]; img read exactly once
__global__ __launch_bounds__(256) void k_ctx(
    const float* __restrict__ img, const float* __restrict__ alphaT,
    float* __restrict__ out) {
  const int dsl = blockIdx.x, b = blockIdx.y;
  const int d0 = dsl * 32;
  const int tid = threadIdx.x;
  if (tid >= 240) return;
  const int t = tid >> 3, dq = tid & 7;  // 30 t x 8 float4-columns
  float4 acc = {0.f, 0.f, 0.f, 0.f};
  const float4* ip =
      reinterpret_cast<const float4*>(img + (size_t)b * kL * kD + d0) + dq;
  const float* ap = alphaT + (size_t)b * kTL + t;
#pragma unroll 4
  for (int l = 0; l < kL; ++l) {
    const float4 v = ip[l * (kD / 4)];
    const float a = ap[l * kT];
    acc.x = fmaf(v.x, a, acc.x);
    acc.y = fmaf(v.y, a, acc.y);
    acc.z = fmaf(v.z, a, acc.z);
    acc.w = fmaf(v.w, a, acc.w);
  }
  *reinterpret_cast<float4*>(out + ((size_t)b * kT + t) * kD + d0 + 4 * dq) =
      acc;
}
}  // namespace

extern "C" void kernel_launch(void* const* d_in, const int* in_sizes, int n_in,
                              void* d_out, int out_size, void* d_ws, size_t ws_size,
                              hipStream_t stream) {
  const float* x = (const float*)d_in[0];
  const float* wordemb = (const float*)d_in[1];
  const float* img = (const float*)d_in[2];
  const float* vw = (const float*)d_in[3];
  // v_b (d_in[4]) cancels in the softmax along with sum(v_w) — unused by design.
  float* out = (float*)d_out;
  float* g_part = (float*)d_ws;                       // 8*32*5880 floats (6.0 MB)
  float* alphaT = g_part + (size_t)8 * kB * kTL;      // 32*5880 floats (751 KB)
  hipLaunchKernelGGL(k_score, dim3(7, 8, kB), dim3(896), 0, stream, x, wordemb,
                     img, vw, g_part);
  hipLaunchKernelGGL(k_alpha, dim3(kB), dim3(256), 0, stream, g_part, alphaT);
  hipLaunchKernelGGL(k_ctx, dim3(16, kB), dim3(256), 0, stream, img, alphaT,
                     out);
}

// Round 3
// 69.611 us; speedup vs baseline: 1.0101x; 1.0101x over previous
//
#include <hip/hip_runtime.h>

namespace {
constexpr int kB = 32, kT = 30, kD = 512, kL = 196;
constexpr float kK = 2.8853900817779268f;  // 2*log2(e)
constexpr int kDS = 64;                    // d per score block
constexpr int kNDS = kD / kDS;             // 8 partials
constexpr int kLC = 14;                    // l per score block
constexpr int kNLC = kL / kLC;             // 14 chunks
constexpr int kTL = kT * kL;               // 5880

// 1-wave blocks. lane=(t:32, ls:2). E[t,d] in VGPRs, vw in SGPRs, F in LDS.
// g_part[ds][b][l][t] = sum over d-slice of vw_d / (1 + E*F)
__global__ __launch_bounds__(64, 4) void k_score(
    const float* __restrict__ x, const float* __restrict__ w,
    const float* __restrict__ img, const float* __restrict__ vw,
    float* __restrict__ g_part) {
  __shared__ __align__(16) float F[kLC * kDS];  // 3.5 KB
  const int lc = blockIdx.x, ds = blockIdx.y, b = blockIdx.z;
  const int l0 = lc * kLC, d0 = ds * kDS;
  const int tid = threadIdx.x;
  const int t = tid & 31, ls = tid >> 5;
  // stage F = exp2(kK*img): 14 rows x 64 d, coalesced, conflict-free
#pragma unroll
  for (int r = 0; r < kLC; ++r) {
    const float v = img[((size_t)(b * kL + l0 + r)) * kD + d0 + tid];
    F[r * kDS + tid] = __builtin_amdgcn_exp2f(kK * v);
  }
  // E registers: per-lane row t (lanes t>=30 clamp to 0; stores guarded)
  const int tc = (t < kT) ? t : 0;
  const float* xr = x + ((size_t)(b * kT + tc)) * kD + d0;
  const float* wr = w + ((size_t)(b * kT + tc)) * kD + d0;
  float E[kDS];
#pragma unroll
  for (int q = 0; q < kDS / 4; ++q) {
    const float4 xv = *(const float4*)(xr + 4 * q);
    const float4 wv = *(const float4*)(wr + 4 * q);
    E[4 * q + 0] = __builtin_amdgcn_exp2f(kK * (xv.x + wv.x));
    E[4 * q + 1] = __builtin_amdgcn_exp2f(kK * (xv.y + wv.y));
    E[4 * q + 2] = __builtin_amdgcn_exp2f(kK * (xv.z + wv.z));
    E[4 * q + 3] = __builtin_amdgcn_exp2f(kK * (xv.w + wv.w));
  }
  __syncthreads();
  float* gb = g_part + (((size_t)ds * kB + b) * kL + l0 + ls) * kT;
#pragma unroll
  for (int p = 0; p < kLC / 2; ++p) {
    const float* Fr = &F[(2 * p + ls) * kDS];
    float a0 = 0.f, a1 = 0.f;
#pragma unroll
    for (int q = 0; q < kDS / 8; ++q) {
      const float4 f0 = *(const float4*)(Fr + 8 * q);
      const float4 f1 = *(const float4*)(Fr + 8 * q + 4);
      const float4 va = *(const float4*)(vw + d0 + 8 * q);      // uniform -> s_load
      const float4 vb = *(const float4*)(vw + d0 + 8 * q + 4);  // uniform -> s_load
      a0 = fmaf(va.x, __builtin_amdgcn_rcpf(fmaf(E[8 * q + 0], f0.x, 1.f)), a0);
      a1 = fmaf(va.y, __builtin_amdgcn_rcpf(fmaf(E[8 * q + 1], f0.y, 1.f)), a1);
      a0 = fmaf(va.z, __builtin_amdgcn_rcpf(fmaf(E[8 * q + 2], f0.z, 1.f)), a0);
      a1 = fmaf(va.w, __builtin_amdgcn_rcpf(fmaf(E[8 * q + 3], f0.w, 1.f)), a1);
      a0 = fmaf(vb.x, __builtin_amdgcn_rcpf(fmaf(E[8 * q + 4], f1.x, 1.f)), a0);
      a1 = fmaf(vb.y, __builtin_amdgcn_rcpf(fmaf(E[8 * q + 5], f1.y, 1.f)), a1);
      a0 = fmaf(vb.z, __builtin_amdgcn_rcpf(fmaf(E[8 * q + 6], f1.z, 1.f)), a0);
      a1 = fmaf(vb.w, __builtin_amdgcn_rcpf(fmaf(E[8 * q + 7], f1.w, 1.f)), a1);
    }
    if (t < kT) gb[(size_t)(2 * p) * kT + t] = a0 + a1;
  }
}

// sum 8 partials, softmax over l, write alphaT[b][l][t]
__global__ __launch_bounds__(1024) void k_alpha(
    const float* __restrict__ g_part, float* __restrict__ alphaT) {
  __shared__ __align__(16) float u[kTL];  // 23.5 KB, layout [l][t]
  const int b = blockIdx.x, tid = threadIdx.x;
  for (int s4 = tid; s4 < kTL / 4; s4 += 1024) {
    float4 a = {0.f, 0.f, 0.f, 0.f};
#pragma unroll
    for (int ds = 0; ds < kNDS; ++ds) {
      const float4 g =
          *(const float4*)&g_part[((size_t)ds * kB + b) * kTL + 4 * s4];
      a.x += g.x; a.y += g.y; a.z += g.z; a.w += g.w;
    }
    *(float4*)&u[4 * s4] = a;
  }
  __syncthreads();
  const int lane = tid & 63, wv = tid >> 6;  // 16 waves
  for (int t = wv; t < kT; t += 16) {
    // weight ~ exp2(min(q) - q), q = kK * g
    const float q0 = u[lane * kT + t] * kK;
    const float q1 = u[(lane + 64) * kT + t] * kK;
    const float q2 = u[(lane + 128) * kT + t] * kK;
    const float q3 = (lane < kL - 192) ? u[(lane + 192) * kT + t] * kK
                                       : __builtin_inff();
    float m = fminf(fminf(q0, q1), fminf(q2, q3));
#pragma unroll
    for (int mm = 1; mm < 64; mm <<= 1) m = fminf(m, __shfl_xor(m, mm, 64));
    const float e0 = __builtin_amdgcn_exp2f(m - q0);
    const float e1 = __builtin_amdgcn_exp2f(m - q1);
    const float e2 = __builtin_amdgcn_exp2f(m - q2);
    const float e3 = (lane < kL - 192) ? __builtin_amdgcn_exp2f(m - q3) : 0.f;
    float s = e0 + e1 + e2 + e3;
#pragma unroll
    for (int mm = 1; mm < 64; mm <<= 1) s += __shfl_xor(s, mm, 64);
    const float rs = __builtin_amdgcn_rcpf(s);
    float* ab = alphaT + (size_t)b * kTL + t;
    ab[lane * kT] = e0 * rs;
    ab[(lane + 64) * kT] = e1 * rs;
    ab[(lane + 128) * kT] = e2 * rs;
    if (lane < kL - 192) ab[(lane + 192) * kT] = e3 * rs;
  }
}

// context[b][t][d] = sum_l img[b][l][d] * alpha[b][l][t]; 6 t-groups of 5
__global__ __launch_bounds__(256) void k_ctx(
    const float* __restrict__ img, const float* __restrict__ alphaT,
    float* __restrict__ out) {
  __shared__ __align__(16) float A[kL][8];  // cols 0..4 used
  const int th = blockIdx.x, b = blockIdx.y;
  const int t0 = th * 5;
  const int tid = threadIdx.x;
  for (int i = tid; i < kL * 5; i += 256) {
    const int l = i / 5, tt = i - 5 * l;
    A[l][tt] = alphaT[(size_t)b * kTL + l * kT + t0 + tt];
  }
  __syncthreads();
  float2 acc[5];
#pragma unroll
  for (int j = 0; j < 5; ++j) acc[j] = {0.f, 0.f};
  const float* ip = img + (size_t)b * kL * kD + 2 * tid;
#pragma unroll 4
  for (int l = 0; l < kL; ++l) {
    const float2 v = *(const float2*)(ip + (size_t)l * kD);
    const float4 a03 = *(const float4*)(&A[l][0]);
    const float a4 = A[l][4];
    acc[0].x = fmaf(v.x, a03.x, acc[0].x);
    acc[0].y = fmaf(v.y, a03.x, acc[0].y);
    acc[1].x = fmaf(v.x, a03.y, acc[1].x);
    acc[1].y = fmaf(v.y, a03.y, acc[1].y);
    acc[2].x = fmaf(v.x, a03.z, acc[2].x);
    acc[2].y = fmaf(v.y, a03.z, acc[2].y);
    acc[3].x = fmaf(v.x, a03.w, acc[3].x);
    acc[3].y = fmaf(v.y, a03.w, acc[3].y);
    acc[4].x = fmaf(v.x, a4, acc[4].x);
    acc[4].y = fmaf(v.y, a4, acc[4].y);
  }
#pragma unroll
  for (int j = 0; j < 5; ++j) {
    *(float2*)(out + ((size_t)(b * kT + t0 + j)) * kD + 2 * tid) = acc[j];
  }
}
}  // namespace

extern "C" void kernel_launch(void* const* d_in, const int* in_sizes, int n_in,
                              void* d_out, int out_size, void* d_ws, size_t ws_size,
                              hipStream_t stream) {
  const float* x = (const float*)d_in[0];
  const float* wordemb = (const float*)d_in[1];
  const float* img = (const float*)d_in[2];
  const float* vw = (const float*)d_in[3];
  // v_b (d_in[4]) cancels in the softmax along with sum(v_w) — unused by design.
  float* out = (float*)d_out;
  float* g_part = (float*)d_ws;                    // 8*32*5880 floats (6.0 MB)
  float* alphaT = g_part + (size_t)kNDS * kB * kTL;  // 32*5880 floats (751 KB)
  hipLaunchKernelGGL(k_score, dim3(kNLC, kNDS, kB), dim3(64), 0, stream, x,
                     wordemb, img, vw, g_part);
  hipLaunchKernelGGL(k_alpha, dim3(kB), dim3(1024), 0, stream, g_part, alphaT);
  hipLaunchKernelGGL(k_ctx, dim3(6, kB), dim3(256), 0, stream, img, alphaT,
                     out);
}

// Round 4
// 55.209 us; speedup vs baseline: 1.2735x; 1.2609x over previous
//
#include <hip/hip_runtime.h>

namespace {
constexpr int kB = 32, kT = 30, kD = 512, kL = 196;
constexpr float kK = 2.8853900817779268f;  // 2*log2(e)
constexpr int kLC = 28;                    // l per score block
constexpr int kNLC = 7;
constexpr int kDS = 128;                   // d per score block
constexpr int kNDS = 4;
constexpr int kNP = 8;                     // partials = kNDS * 2 wave-halves
constexpr int kTL = kT * kL;               // 5880

// tanh(z) = 1 - 2/(1 + 2^(kK*z)); e[t,l] = C - 2*sum_d vw_d/(1+E*F),
// C cancels in softmax. E = 2^(kK(x+w)) (t-dep), F = 2^(kK*img) (l-dep).
// g_part[p][b][l][t], p = ds*2+dh indexes a 64-wide d slice.
__global__ __launch_bounds__(128) void k_score(
    const float* __restrict__ x, const float* __restrict__ w,
    const float* __restrict__ img, const float* __restrict__ vw,
    float* __restrict__ g_part) {
  __shared__ __align__(16) float4 E4[32 * 32];   // [t][c4 ^ (t&7)]
  __shared__ __align__(16) float4 F4[kLC * 32];  // [r][c4 ^ (r&7)]
  const int lc = blockIdx.x, ds = blockIdx.y, b = blockIdx.z;
  const int l0 = lc * kLC, d0 = ds * kDS;
  const int tid = threadIdx.x;
  // stage E rows 0..29 (rows 30,31 = 1.0), coalesced float4, swizzled store
#pragma unroll
  for (int k = 0; k < 8; ++k) {
    const int i = tid + k * 128;
    const int t = i >> 5, c4 = i & 31;
    float4 v = {1.f, 1.f, 1.f, 1.f};
    if (t < kT) {
      const size_t gi = ((size_t)(b * kT + t)) * kD + d0 + 4 * c4;
      const float4 xv = *(const float4*)(x + gi);
      const float4 wv = *(const float4*)(w + gi);
      v.x = __builtin_amdgcn_exp2f(kK * (xv.x + wv.x));
      v.y = __builtin_amdgcn_exp2f(kK * (xv.y + wv.y));
      v.z = __builtin_amdgcn_exp2f(kK * (xv.z + wv.z));
      v.w = __builtin_amdgcn_exp2f(kK * (xv.w + wv.w));
    }
    E4[t * 32 + (c4 ^ (t & 7))] = v;
  }
  // stage F rows 0..27
#pragma unroll
  for (int k = 0; k < 7; ++k) {
    const int i = tid + k * 128;
    const int r = i >> 5, c4 = i & 31;
    const size_t gi = ((size_t)(b * kL + l0 + r)) * kD + d0 + 4 * c4;
    const float4 gv = *(const float4*)(img + gi);
    float4 v;
    v.x = __builtin_amdgcn_exp2f(kK * gv.x);
    v.y = __builtin_amdgcn_exp2f(kK * gv.y);
    v.z = __builtin_amdgcn_exp2f(kK * gv.z);
    v.w = __builtin_amdgcn_exp2f(kK * gv.w);
    F4[r * 32 + (c4 ^ (r & 7))] = v;
  }
  __syncthreads();
  const int lane = tid & 63;
  const int tt = lane & 15, lt = lane >> 4;  // 16 t-pairs x 4 l-groups
  const int dh = tid >> 6;                   // wave owns a 64-d half
  const int sw = tt & 7;                     // (tt+16)&7 == tt&7
  float acc0[7], acc1[7];
#pragma unroll
  for (int j = 0; j < 7; ++j) { acc0[j] = 0.f; acc1[j] = 0.f; }
  const float4* Ep0 = &E4[tt * 32];
  const float4* Ep1 = &E4[(tt + 16) * 32];
#pragma unroll 4
  for (int q = 0; q < 16; ++q) {
    const int c4 = dh * 16 + q;
    const float4 e0 = Ep0[c4 ^ sw];
    const float4 e1 = Ep1[c4 ^ sw];
    const float4 vv = *(const float4*)(vw + d0 + 4 * c4);  // uniform -> s_load
#pragma unroll
    for (int j = 0; j < 7; ++j) {
      const int r = lt * 7 + j;
      const float4 f = F4[r * 32 + (c4 ^ (r & 7))];
      acc0[j] = fmaf(vv.x, __builtin_amdgcn_rcpf(fmaf(e0.x, f.x, 1.f)), acc0[j]);
      acc0[j] = fmaf(vv.y, __builtin_amdgcn_rcpf(fmaf(e0.y, f.y, 1.f)), acc0[j]);
      acc0[j] = fmaf(vv.z, __builtin_amdgcn_rcpf(fmaf(e0.z, f.z, 1.f)), acc0[j]);
      acc0[j] = fmaf(vv.w, __builtin_amdgcn_rcpf(fmaf(e0.w, f.w, 1.f)), acc0[j]);
      acc1[j] = fmaf(vv.x, __builtin_amdgcn_rcpf(fmaf(e1.x, f.x, 1.f)), acc1[j]);
      acc1[j] = fmaf(vv.y, __builtin_amdgcn_rcpf(fmaf(e1.y, f.y, 1.f)), acc1[j]);
      acc1[j] = fmaf(vv.z, __builtin_amdgcn_rcpf(fmaf(e1.z, f.z, 1.f)), acc1[j]);
      acc1[j] = fmaf(vv.w, __builtin_amdgcn_rcpf(fmaf(e1.w, f.w, 1.f)), acc1[j]);
    }
  }
  const int p = ds * 2 + dh;
  float* gb = g_part + ((size_t)(p * kB + b)) * kTL;
#pragma unroll
  for (int j = 0; j < 7; ++j) {
    const int l = l0 + lt * 7 + j;
    gb[l * kT + tt] = acc0[j];
    if (tt < kT - 16) gb[l * kT + tt + 16] = acc1[j];
  }
}

// sum 8 partials, softmax over l, write alphaT[b][l][t]
__global__ __launch_bounds__(1024) void k_alpha(
    const float* __restrict__ g_part, float* __restrict__ alphaT) {
  __shared__ __align__(16) float u[kTL];  // [l][t]
  const int b = blockIdx.x, tid = threadIdx.x;
  for (int s4 = tid; s4 < kTL / 4; s4 += 1024) {
    float4 a = {0.f, 0.f, 0.f, 0.f};
#pragma unroll
    for (int p = 0; p < kNP; ++p) {
      const float4 g =
          *(const float4*)&g_part[((size_t)(p * kB + b)) * kTL + 4 * s4];
      a.x += g.x; a.y += g.y; a.z += g.z; a.w += g.w;
    }
    *(float4*)&u[4 * s4] = a;
  }
  __syncthreads();
  const int lane = tid & 63, wv = tid >> 6;  // 16 waves
  for (int t = wv; t < kT; t += 16) {
    // alpha ~ 2^(min(q) - q), q = kK*g  (e = C - 2g; C cancels)
    const float q0 = u[lane * kT + t] * kK;
    const float q1 = u[(lane + 64) * kT + t] * kK;
    const float q2 = u[(lane + 128) * kT + t] * kK;
    const float q3 = (lane < kL - 192) ? u[(lane + 192) * kT + t] * kK
                                       : __builtin_inff();
    float m = fminf(fminf(q0, q1), fminf(q2, q3));
#pragma unroll
    for (int mm = 1; mm < 64; mm <<= 1) m = fminf(m, __shfl_xor(m, mm, 64));
    const float e0 = __builtin_amdgcn_exp2f(m - q0);
    const float e1 = __builtin_amdgcn_exp2f(m - q1);
    const float e2 = __builtin_amdgcn_exp2f(m - q2);
    const float e3 = (lane < kL - 192) ? __builtin_amdgcn_exp2f(m - q3) : 0.f;
    float s = e0 + e1 + e2 + e3;
#pragma unroll
    for (int mm = 1; mm < 64; mm <<= 1) s += __shfl_xor(s, mm, 64);
    const float rs = __builtin_amdgcn_rcpf(s);
    float* ab = alphaT + (size_t)b * kTL + t;
    ab[lane * kT] = e0 * rs;
    ab[(lane + 64) * kT] = e1 * rs;
    ab[(lane + 128) * kT] = e2 * rs;
    if (lane < kL - 192) ab[(lane + 192) * kT] = e3 * rs;
  }
}

// context[b][t][d] = sum_l img[b][l][d] * alpha[b][l][t]
// grid (6 t-groups x 2 d-halves x B), 128 threads (256 d each, float2/lane)
__global__ __launch_bounds__(128) void k_ctx(
    const float* __restrict__ img, const float* __restrict__ alphaT,
    float* __restrict__ out) {
  __shared__ __align__(16) float A[kL][8];  // cols 0..4 used
  const int tg = blockIdx.x, dh = blockIdx.y, b = blockIdx.z;
  const int t0 = tg * 5, doff = dh * 256;
  const int tid = threadIdx.x;
  for (int i = tid; i < kL * 5; i += 128) {
    const int l = i / 5, tt = i - 5 * l;
    A[l][tt] = alphaT[(size_t)b * kTL + l * kT + t0 + tt];
  }
  __syncthreads();
  float2 acc[5];
#pragma unroll
  for (int j = 0; j < 5; ++j) acc[j] = {0.f, 0.f};
  const float* ip = img + (size_t)b * kL * kD + doff + 2 * tid;
#pragma unroll 4
  for (int l = 0; l < kL; ++l) {
    const float2 v = *(const float2*)(ip + (size_t)l * kD);
    const float4 a03 = *(const float4*)(&A[l][0]);
    const float a4 = A[l][4];
    acc[0].x = fmaf(v.x, a03.x, acc[0].x);
    acc[0].y = fmaf(v.y, a03.x, acc[0].y);
    acc[1].x = fmaf(v.x, a03.y, acc[1].x);
    acc[1].y = fmaf(v.y, a03.y, acc[1].y);
    acc[2].x = fmaf(v.x, a03.z, acc[2].x);
    acc[2].y = fmaf(v.y, a03.z, acc[2].y);
    acc[3].x = fmaf(v.x, a03.w, acc[3].x);
    acc[3].y = fmaf(v.y, a03.w, acc[3].y);
    acc[4].x = fmaf(v.x, a4, acc[4].x);
    acc[4].y = fmaf(v.y, a4, acc[4].y);
  }
#pragma unroll
  for (int j = 0; j < 5; ++j) {
    *(float2*)(out + ((size_t)(b * kT + t0 + j)) * kD + doff + 2 * tid) =
        acc[j];
  }
}
}  // namespace

extern "C" void kernel_launch(void* const* d_in, const int* in_sizes, int n_in,
                              void* d_out, int out_size, void* d_ws, size_t ws_size,
                              hipStream_t stream) {
  const float* x = (const float*)d_in[0];
  const float* wordemb = (const float*)d_in[1];
  const float* img = (const float*)d_in[2];
  const float* vw = (const float*)d_in[3];
  // v_b (d_in[4]) cancels in the softmax along with sum(v_w) — unused by design.
  float* out = (float*)d_out;
  float* g_part = (float*)d_ws;                     // 8*32*5880 floats (6.0 MB)
  float* alphaT = g_part + (size_t)kNP * kB * kTL;  // 32*5880 floats (751 KB)
  hipLaunchKernelGGL(k_score, dim3(kNLC, kNDS, kB), dim3(128), 0, stream, x,
                     wordemb, img, vw, g_part);
  hipLaunchKernelGGL(k_alpha, dim3(kB), dim3(1024), 0, stream, g_part, alphaT);
  hipLaunchKernelGGL(k_ctx, dim3(6, 2, kB), dim3(128), 0, stream, img, alphaT,
                     out);
}